// Round 4
// baseline (548.077 us; speedup 1.0000x reference)
//
#include <hip/hip_runtime.h>

// LSTMNextToken: embed-gather -> 2x LSTM -> LayerNorm -> tied-embedding head.
// I/O dtypes: float tensors are float32; x is int32. Internals f16/bf16 MFMA.
//
// R9 pipeline:
//  k_ew   : EW[v][g] = embed[v]@Wih0^T + bih0 + bhh0   (433x480 f32, L2-resident)
//  k_prep : embF bf16 frag-major (head B); w1F f16 frag-major (Wih1 B, streamed
//           per step from L2); b1s = bih1+bhh1
//  k_rec  : 512 thr = 8 waves, TB=16, CROSS-LAYER PIPELINED: super-step s does
//           layer0(t=s) and layer1(t=s-1) in one MFMA phase (h0 handoff via
//           hLh0 LDS — hb0 global round-trip eliminated), both gate-maths +
//           shuffle-LN in phase B, head(t=s-2) issued in phase A from
//           hnLD[(s)&1]. 2 barriers/super-step, 17 super-steps.
// R7/R8 lesson: 1024-thr blocks get a 64-VGPR budget on this toolchain ->
// massive spill (424/30 MB FETCH). 512-thr blocks (R6) give ~256 effective
// regs, no spill. So R9 stays 8 waves and instead removes k_rec0's serial
// 45 us by overlapping it with k_rec1's chain. Resident weights capped at
// 2 sets (Whh0,Whh1 = 128 regs); Wih1 streamed from w1F (L2). LDS: 2*30976
// + 2*4352 + 8704 + 1024 = 80384 B.

#define VSZ 433
#define DIM 120
#define BSZ 4096
#define SEQ 16
#define H4  480
#define KP  128
#define NPAD 448
#define NT_HEAD 28
#define TB  16
#define GP  484          // gates LDS row pad (2-way banks = free)
#define HP  136          // h-state LDS row pad in f16/bf16

typedef unsigned int   u32;
typedef unsigned short u16;
typedef __attribute__((ext_vector_type(8))) short    v8bf;
typedef __attribute__((ext_vector_type(8))) _Float16 v8h;
typedef __attribute__((ext_vector_type(4))) float    v4f;

__device__ __forceinline__ u16 f2bf(float f){ // RNE
  union{float f;u32 u;}z; z.f=f;
  u32 u = z.u + 0x7fffu + ((z.u>>16)&1u);
  return (u16)(u>>16);
}
__device__ __forceinline__ u32 packh2(float a, float b){
  union{_Float16 h[2]; u32 u;} z;
  z.h[0] = (_Float16)a; z.h[1] = (_Float16)b;
  return z.u;
}

// ---------------- workspace layout (bytes, 256-aligned) ----------------
#define EW_OFF   0u          // 433*480*4   = 831360
#define B1S_OFF  831488u     // 480*4       = 1920
#define EMBF_OFF 833408u     // 448*128*2   = 114688
#define W1F_OFF  948096u     // 30*4*64*8*2 = 122880   (end ~1.07 MB)

// ---------------- k_ew ----------------
__global__ __launch_bounds__(512) void k_ew(const float* __restrict__ embed,
                                            const float* __restrict__ Wih0,
                                            const float* __restrict__ bih0,
                                            const float* __restrict__ bhh0,
                                            float* __restrict__ EW)
{
  __shared__ float e[DIM];
  const int v = blockIdx.x, tid = threadIdx.x;
  if (tid < DIM) e[tid] = embed[v*DIM + tid];
  __syncthreads();
  if (tid < H4) {
    float acc = bih0[tid] + bhh0[tid];
    #pragma unroll
    for (int k0 = 0; k0 < DIM; k0 += 4) {
      float4 w = *(const float4*)(Wih0 + tid*DIM + k0);
      acc = fmaf(e[k0+0], w.x, acc);
      acc = fmaf(e[k0+1], w.y, acc);
      acc = fmaf(e[k0+2], w.z, acc);
      acc = fmaf(e[k0+3], w.w, acc);
    }
    EW[v*H4 + tid] = acc;
  }
}

// ---------------- k_prep: embF (bf16 frag-major) + b1s + w1F (f16 frag-major) ----------------
// frag-major index: ((f*64 + lane)*8 + j), f = nt*4 + kt, lane = quad*16 + cl.
// embF[f,lane,j] = bf16(embed[nt*16+cl][kt*32+quad*8+j])  (0-padded)
// w1F [f,lane,j] = f16 (Wih1 [nt*16+cl][kt*32+quad*8+j])  (0-padded, nt<30)
__global__ __launch_bounds__(256) void k_prep(const float* __restrict__ embed,
                                              const float* __restrict__ bih1,
                                              const float* __restrict__ bhh1,
                                              const float* __restrict__ Wih1,
                                              u16* __restrict__ embF,
                                              float* __restrict__ b1s,
                                              _Float16* __restrict__ w1F)
{
  const int idx = blockIdx.x*256 + threadIdx.x;
  if (idx < NPAD*KP) {
    int n = idx >> 7, k = idx & 127;
    int nt = n >> 4, cl = n & 15, kt = k >> 5, quad = (k >> 3) & 3, j = k & 7;
    int fidx = ((((nt*4 + kt)*4 + quad)*16 + cl) << 3) + j;
    embF[fidx] = (n < VSZ && k < DIM) ? f2bf(embed[n*DIM + k]) : (u16)0;
  } else if (idx < NPAD*KP + H4) {
    int g = idx - NPAD*KP;
    b1s[g] = bih1[g] + bhh1[g];
  } else if (idx < NPAD*KP + H4 + 30*4*512) {
    int i0 = idx - (NPAD*KP + H4);
    int f = i0 >> 9, r = i0 & 511, lane = r >> 3, j = r & 7;
    int nt = f >> 2, kt = f & 3, cl = lane & 15, quad = lane >> 4;
    int k = kt*32 + quad*8 + j, n = nt*16 + cl;
    w1F[i0] = (k < DIM) ? (_Float16)Wih1[n*DIM + k] : (_Float16)0.f;
  }
}

// ---------------- k_rec: fused 2-layer LSTM + LN + head, cross-layer pipelined ----------------
__global__ __launch_bounds__(512) void k_rec(const float* __restrict__ Whh0,
                                             const float* __restrict__ EW,
                                             const int* __restrict__ x,
                                             const float* __restrict__ Whh1,
                                             const float* __restrict__ b1s,
                                             const float* __restrict__ gamma,
                                             const float* __restrict__ beta,
                                             const _Float16* __restrict__ w1F,
                                             const u16* __restrict__ embF,
                                             float* __restrict__ out)
{
  __shared__ float gLs0[TB][GP];                    // 30976 B  layer0 gates
  __shared__ float gLs1[TB][GP];                    // 30976 B  layer1 gates
  __shared__ __align__(16) _Float16 hLh0[TB][HP];   //  4352 B  h0 state (f16)
  __shared__ __align__(16) _Float16 hLh1[TB][HP];   //  4352 B  h1 state (f16)
  __shared__ __align__(16) u16 hnLD[2][TB][HP];     //  8704 B  LN'd h1 (bf16, dbuf)
  __shared__ int xL[TB*SEQ];                        //  1024 B
  // total 80384 B

  const int tid  = threadIdx.x;
  const int wave = tid >> 6, lane = tid & 63;
  const int cl   = lane & 15, quad = lane >> 4;
  const int b0   = blockIdx.x * TB;

  for (int i = tid; i < TB*SEQ; i += 512) xL[i] = x[b0*SEQ + i];
  for (int i = tid; i < TB*HP; i += 512) {
    (&hLh0[0][0])[i] = (_Float16)0.f;
    (&hLh1[0][0])[i] = (_Float16)0.f;
  }

  // resident weights: Whh0 (layer0 recurrent), Whh1 (layer1 recurrent) = 128 regs
  v8h Bf0[4][4], Bh1[4][4];
  float bias[4];
  #pragma unroll
  for (int i = 0; i < 4; ++i) {
    const int nt = wave*4 + i;
    const bool vld = (nt < 30);
    const int n = vld ? nt*16 + cl : 0;
    bias[i] = vld ? b1s[n] : 0.f;
    #pragma unroll
    for (int kt = 0; kt < 4; ++kt) {
      const int k0 = kt*32 + quad*8;
      v8h f0 = {0,0,0,0,0,0,0,0}, f1 = {0,0,0,0,0,0,0,0};
      if (vld && k0 < DIM) {
        float4 q0 = *(const float4*)(Whh0 + n*DIM + k0);
        float4 q1 = *(const float4*)(Whh0 + n*DIM + k0 + 4);
        f0[0]=(_Float16)q0.x; f0[1]=(_Float16)q0.y; f0[2]=(_Float16)q0.z; f0[3]=(_Float16)q0.w;
        f0[4]=(_Float16)q1.x; f0[5]=(_Float16)q1.y; f0[6]=(_Float16)q1.z; f0[7]=(_Float16)q1.w;
        float4 p0 = *(const float4*)(Whh1 + n*DIM + k0);
        float4 p1 = *(const float4*)(Whh1 + n*DIM + k0 + 4);
        f1[0]=(_Float16)p0.x; f1[1]=(_Float16)p0.y; f1[2]=(_Float16)p0.z; f1[3]=(_Float16)p0.w;
        f1[4]=(_Float16)p1.x; f1[5]=(_Float16)p1.y; f1[6]=(_Float16)p1.z; f1[7]=(_Float16)p1.w;
      }
      Bf0[i][kt] = f0;
      Bh1[i][kt] = f1;
    }
  }

  float srcv[4][4];
  auto load_src = [&](int t) {
    #pragma unroll
    for (int i = 0; i < 4; ++i) {
      const int nt = wave*4 + i;
      if (nt < 30) {
        const int n = nt*16 + cl;
        #pragma unroll
        for (int r = 0; r < 4; ++r)
          srcv[i][r] = EW[(size_t)xL[(quad*4 + r)*SEQ + t]*H4 + n];
      }
    }
  };
  load_src(0);

  // phase-B mapping: wave owns rows {2w,2w+1}; lane l<60 owns dims {2l,2l+1}
  const int prow = wave*2;
  const bool act = lane < 60;
  const int d0   = lane*2;
  float gmm[2] = {0.f, 0.f}, bta[2] = {0.f, 0.f};
  if (act) {
    gmm[0] = gamma[d0]; gmm[1] = gamma[d0+1];
    bta[0] = beta[d0];  bta[1] = beta[d0+1];
  }
  float C0[2][2] = {{0.f,0.f},{0.f,0.f}};
  float C1[2][2] = {{0.f,0.f},{0.f,0.f}};
  __syncthreads();   // prologue: hLh init + xL staged

  for (int s = 0; s <= SEQ; ++s) {
    // ================= phase A: MFMA =================
    // layer0 computes gates0 for t=s (A = h0[s-1] = hLh0)
    // layer1 computes gates1 for t=s-1 (A0 = h0[s-1] = hLh0 shared read,
    //                                   A1 = h1[s-2] = hLh1, B_ih streamed w1F)
    v4f acc0[4], acc1[4];
    #pragma unroll
    for (int i = 0; i < 4; ++i) {
      acc0[i][0]=srcv[i][0]; acc0[i][1]=srcv[i][1];
      acc0[i][2]=srcv[i][2]; acc0[i][3]=srcv[i][3];
      acc1[i] = (v4f){bias[i], bias[i], bias[i], bias[i]};
    }
    #pragma unroll
    for (int kt = 0; kt < 4; ++kt) {
      v8h hbF = *(const v8h*)&hLh0[cl][kt*32 + quad*8];
      v8h h1F = *(const v8h*)&hLh1[cl][kt*32 + quad*8];
      #pragma unroll
      for (int i = 0; i < 4; ++i) {
        const int nt = wave*4 + i;
        if (nt < 30) {
          if (s < SEQ)
            acc0[i] = __builtin_amdgcn_mfma_f32_16x16x32_f16(hbF, Bf0[i][kt], acc0[i], 0, 0, 0);
          if (s >= 1) {
            v8h w1f = *(const v8h*)&w1F[(((size_t)nt*4 + kt)*64 + lane)*8];
            acc1[i] = __builtin_amdgcn_mfma_f32_16x16x32_f16(hbF, w1f, acc1[i], 0, 0, 0);
            acc1[i] = __builtin_amdgcn_mfma_f32_16x16x32_f16(h1F, Bh1[i][kt], acc1[i], 0, 0, 0);
          }
        }
      }
    }
    // head for t=s-2 (hnLD parity (s-2)&1 == s&1), overlaps the LSTM chain
    if (s >= 2) {
      const int t = s - 2;
      v8bf a[4];
      #pragma unroll
      for (int kt = 0; kt < 4; ++kt)
        a[kt] = *(const v8bf*)&hnLD[s & 1][cl][kt*32 + quad*8];
      #pragma unroll
      for (int j = 0; j < 4; ++j) {
        const int nth = wave + 8*j;         // waves 0-3: 4 tiles, 4-7: 3 tiles
        if (nth < NT_HEAD) {
          v8bf bfr[4];
          #pragma unroll
          for (int kt = 0; kt < 4; ++kt)
            bfr[kt] = *(const v8bf*)&embF[(((size_t)nth*4 + kt)*64 + lane)*8];
          v4f hacc = {0.f, 0.f, 0.f, 0.f};
          #pragma unroll
          for (int kt = 0; kt < 4; ++kt)
            hacc = __builtin_amdgcn_mfma_f32_16x16x32_bf16(a[kt], bfr[kt], hacc, 0, 0, 0);
          const int n = nth*16 + cl;
          if (n < VSZ) {
            #pragma unroll
            for (int r = 0; r < 4; ++r)
              out[((size_t)(b0 + quad*4 + r)*SEQ + t)*VSZ + n] = hacc[r];
          }
        }
      }
    }
    if (s + 1 < SEQ) load_src(s + 1);
    #pragma unroll
    for (int i = 0; i < 4; ++i) {
      const int nt = wave*4 + i;
      if (nt < 30) {
        #pragma unroll
        for (int r = 0; r < 4; ++r) {
          if (s < SEQ) gLs0[quad*4 + r][nt*16 + cl] = acc0[i][r];
          if (s >= 1) gLs1[quad*4 + r][nt*16 + cl] = acc1[i][r];
        }
      }
    }
    __syncthreads();   // sync1: gates visible

    // ================= phase B: gate math =================
    if (s < SEQ) {   // layer0: h0[s]
      #pragma unroll
      for (int rr = 0; rr < 2; ++rr) {
        const int row = prow + rr;
        if (act) {
          const float2 gi = *(const float2*)&gLs0[row][d0      ];
          const float2 gf = *(const float2*)&gLs0[row][d0 + 120];
          const float2 gg = *(const float2*)&gLs0[row][d0 + 240];
          const float2 go = *(const float2*)&gLs0[row][d0 + 360];
          float h2[2];
          #pragma unroll
          for (int k = 0; k < 2; ++k) {
            const float vi = k ? gi.y : gi.x, vf = k ? gf.y : gf.x;
            const float vg = k ? gg.y : gg.x, vo = k ? go.y : go.x;
            const float si = 1.f / (1.f + __expf(-vi));
            const float sf = 1.f / (1.f + __expf(-vf));
            const float tg = 1.f - 2.f / (__expf(2.f*vg) + 1.f);
            const float so = 1.f / (1.f + __expf(-vo));
            const float c  = sf * C0[rr][k] + si * tg;
            C0[rr][k] = c;
            const float tc = 1.f - 2.f / (__expf(2.f*c) + 1.f);
            h2[k] = so * tc;
          }
          *(u32*)&hLh0[row][d0] = packh2(h2[0], h2[1]);
        }
      }
    }
    if (s >= 1) {    // layer1: h1[s-1] + LN -> hnLD[(s-1)&1]
      float h2[2][2] = {{0.f,0.f},{0.f,0.f}};
      float s1[2] = {0.f, 0.f}, s2[2] = {0.f, 0.f};
      #pragma unroll
      for (int rr = 0; rr < 2; ++rr) {
        const int row = prow + rr;
        if (act) {
          const float2 gi = *(const float2*)&gLs1[row][d0      ];
          const float2 gf = *(const float2*)&gLs1[row][d0 + 120];
          const float2 gg = *(const float2*)&gLs1[row][d0 + 240];
          const float2 go = *(const float2*)&gLs1[row][d0 + 360];
          #pragma unroll
          for (int k = 0; k < 2; ++k) {
            const float vi = k ? gi.y : gi.x, vf = k ? gf.y : gf.x;
            const float vg = k ? gg.y : gg.x, vo = k ? go.y : go.x;
            const float si = 1.f / (1.f + __expf(-vi));
            const float sf = 1.f / (1.f + __expf(-vf));
            const float tg = 1.f - 2.f / (__expf(2.f*vg) + 1.f);
            const float so = 1.f / (1.f + __expf(-vo));
            const float c  = sf * C1[rr][k] + si * tg;
            C1[rr][k] = c;
            const float tc = 1.f - 2.f / (__expf(2.f*c) + 1.f);
            const float h  = so * tc;
            h2[rr][k] = h;
            s1[rr] += h;
            s2[rr] = fmaf(h, h, s2[rr]);
          }
          *(u32*)&hLh1[row][d0] = packh2(h2[rr][0], h2[rr][1]);
        }
      }
      #pragma unroll
      for (int m = 32; m >= 1; m >>= 1) {
        s1[0] += __shfl_xor(s1[0], m);
        s2[0] += __shfl_xor(s2[0], m);
        s1[1] += __shfl_xor(s1[1], m);
        s2[1] += __shfl_xor(s2[1], m);
      }
      #pragma unroll
      for (int rr = 0; rr < 2; ++rr) {
        const int row = prow + rr;
        const float mu = s1[rr] * (1.f/DIM);
        const float var = s2[rr] * (1.f/DIM) - mu*mu;
        const float rs = rsqrtf(var + 1e-5f);
        if (act) {
          const float v0 = fmaf((h2[rr][0] - mu)*rs, gmm[0], bta[0]);
          const float v1 = fmaf((h2[rr][1] - mu)*rs, gmm[1], bta[1]);
          *(u32*)&hnLD[(s-1) & 1][row][d0] = (u32)f2bf(v0) | ((u32)f2bf(v1) << 16);
        } else {
          *(u32*)&hnLD[(s-1) & 1][row][120 + 2*(lane - 60)] = 0u;
        }
      }
    }
    __syncthreads();   // sync2: hLh0/hLh1/hnLD stable
  }

  // tail: head for t=SEQ-1 (parity 1)
  {
    const int t = SEQ - 1;
    v8bf a[4];
    #pragma unroll
    for (int kt = 0; kt < 4; ++kt)
      a[kt] = *(const v8bf*)&hnLD[1][cl][kt*32 + quad*8];
    #pragma unroll
    for (int j = 0; j < 4; ++j) {
      const int nth = wave + 8*j;
      if (nth < NT_HEAD) {
        v8bf bfr[4];
        #pragma unroll
        for (int kt = 0; kt < 4; ++kt)
          bfr[kt] = *(const v8bf*)&embF[(((size_t)nth*4 + kt)*64 + lane)*8];
        v4f hacc = {0.f, 0.f, 0.f, 0.f};
        #pragma unroll
        for (int kt = 0; kt < 4; ++kt)
          hacc = __builtin_amdgcn_mfma_f32_16x16x32_bf16(a[kt], bfr[kt], hacc, 0, 0, 0);
        const int n = nth*16 + cl;
        if (n < VSZ) {
          #pragma unroll
          for (int r = 0; r < 4; ++r)
            out[((size_t)(b0 + quad*4 + r)*SEQ + t)*VSZ + n] = hacc[r];
        }
      }
    }
  }
}

// ---------------- launch ----------------
extern "C" void kernel_launch(void* const* d_in, const int* in_sizes, int n_in,
                              void* d_out, int out_size, void* d_ws, size_t ws_size,
                              hipStream_t stream)
{
  (void)in_sizes; (void)n_in; (void)out_size; (void)ws_size;
  const int*   x     = (const int*)d_in[0];
  const float* embed = (const float*)d_in[1];
  const float* Wih0  = (const float*)d_in[2];
  const float* Whh0  = (const float*)d_in[3];
  const float* bih0  = (const float*)d_in[4];
  const float* bhh0  = (const float*)d_in[5];
  const float* Wih1  = (const float*)d_in[6];
  const float* Whh1  = (const float*)d_in[7];
  const float* bih1  = (const float*)d_in[8];
  const float* bhh1  = (const float*)d_in[9];
  const float* gamma = (const float*)d_in[10];
  const float* beta  = (const float*)d_in[11];

  char* ws = (char*)d_ws;
  float*     EW   = (float*)(ws + EW_OFF);
  float*     b1s  = (float*)(ws + B1S_OFF);
  u16*       embF = (u16*)(ws + EMBF_OFF);
  _Float16*  w1F  = (_Float16*)(ws + W1F_OFF);

  k_ew  <<<VSZ, 512, 0, stream>>>(embed, Wih0, bih0, bhh0, EW);
  k_prep<<<466, 256, 0, stream>>>(embed, bih1, bhh1, Wih1, embF, b1s, w1F);
  k_rec <<<BSZ/TB, 512, 0, stream>>>(Whh0, EW, x, Whh1, b1s, gamma, beta, w1F, embF, (float*)d_out);
}

// Round 6
// 402.614 us; speedup vs baseline: 1.3613x; 1.3613x over previous
//
#include <hip/hip_runtime.h>

// LSTMNextToken: embed-gather -> 2x LSTM -> LayerNorm -> tied-embedding head.
// I/O dtypes: float tensors are float32; x is int32. Internals f16/bf16 MFMA.
//
// R11 pipeline (= R6 with k_rec0 at TB0=8 for 2 blocks/CU):
//  k_ew    : EW[v][g] = embed[v]@Wih0^T + bih0 + bhh0       (433x480 f32, L2-resident)
//  k_prep2 : embP bf16 [448][128] zero-padded; b1s = bih1+bhh1 (f32)
//  k_rec0  : TB0=8, grid 512, launch_bounds(512,4) -> 2 blocks/CU. Wave owns
//            4 n-tiles (Whh0 resident, 64 reg ~110 total, fits 128 cap) +
//            1 phase-B row. MFMA rows 8..15 are zero-padded garbage (A rows
//            8..15 read zeroed LDS) and are never stored -> per-row math
//            bit-identical to R6. hb0 f16 t-major unchanged.
//  k_rec1  : EXACT R6: TB=16, grid 256, MFMA LSTM layer 1 + shuffle-LN +
//            fused tied-embedding head (embL staged in LDS).
// R10 failed (absmax 3.1e-2) with 3 simultaneous changes; R11 bisects:
// pass => TB=8 garbage-row scheme OK (bug was rec1/w1F side);
// fail => zero-row A-frag assumption broken, abandon direction.

#define VSZ 433
#define DIM 120
#define BSZ 4096
#define SEQ 16
#define H4  480
#define MTOT (BSZ*SEQ)   // 65536
#define KP  128          // padded K for MFMA
#define NPAD 448         // padded vocab for head
#define NT_HEAD (NPAD/16) // 28 head n-tiles
#define TB  16           // batch rows per rec1 block
#define TB0 8            // batch rows per rec0 block (R11: 2 blocks/CU)
#define GP  484          // gates LDS row pad (484%32=4 -> 2-way banks = free)
#define HP  136          // h-state LDS row pad in f16/bf16

typedef unsigned int   u32;
typedef unsigned short u16;
typedef __attribute__((ext_vector_type(8))) short    v8bf; // 8 x bf16
typedef __attribute__((ext_vector_type(8))) _Float16 v8h;  // 8 x f16
typedef __attribute__((ext_vector_type(4))) float    v4f;  // MFMA acc

__device__ __forceinline__ u16 f2bf(float f){ // RNE
  union{float f;u32 u;}z; z.f=f;
  u32 u = z.u + 0x7fffu + ((z.u>>16)&1u);
  return (u16)(u>>16);
}
__device__ __forceinline__ u32 packh2(float a, float b){
  union{_Float16 h[2]; u32 u;} z;
  z.h[0] = (_Float16)a; z.h[1] = (_Float16)b;
  return z.u;
}

// ---------------- workspace layout (bytes, 256-aligned) ----------------
#define EW_OFF   0u          // 433*480*4   = 831360
#define B1S_OFF  831488u     // 480*4       = 1920
#define EMBP_OFF 833408u     // 448*128*2   = 114688
#define HB0_OFF  948096u     // 65536*128*2 = 16777216  (f16, t-major)

// ---------------- k_ew ----------------
__global__ __launch_bounds__(512) void k_ew(const float* __restrict__ embed,
                                            const float* __restrict__ Wih0,
                                            const float* __restrict__ bih0,
                                            const float* __restrict__ bhh0,
                                            float* __restrict__ EW)
{
  __shared__ float e[DIM];
  const int v = blockIdx.x, tid = threadIdx.x;
  if (tid < DIM) e[tid] = embed[v*DIM + tid];
  __syncthreads();
  if (tid < H4) {
    float acc = bih0[tid] + bhh0[tid];
    #pragma unroll
    for (int k0 = 0; k0 < DIM; k0 += 4) {
      float4 w = *(const float4*)(Wih0 + tid*DIM + k0);
      acc = fmaf(e[k0+0], w.x, acc);
      acc = fmaf(e[k0+1], w.y, acc);
      acc = fmaf(e[k0+2], w.z, acc);
      acc = fmaf(e[k0+3], w.w, acc);
    }
    EW[v*H4 + tid] = acc;
  }
}

// ---------------- k_prep2: embP bf16 padded + b1s ----------------
__global__ __launch_bounds__(256) void k_prep2(const float* __restrict__ embed,
                                               const float* __restrict__ bih1,
                                               const float* __restrict__ bhh1,
                                               u16* __restrict__ embP,
                                               float* __restrict__ b1s)
{
  const int idx = blockIdx.x*256 + threadIdx.x;
  if (idx < NPAD*KP) {
    int n = idx >> 7, k = idx & 127;
    embP[idx] = (n < VSZ && k < DIM) ? f2bf(embed[n*DIM + k]) : (u16)0;
  } else if (idx < NPAD*KP + H4) {
    int g = idx - NPAD*KP;
    b1s[g] = bih1[g] + bhh1[g];
  }
}

// ---------------- k_rec0: MFMA LSTM layer 0, TB0=8, 2 blocks/CU ----------------
// 512 thr = 8 waves. Wave owns n-tiles wave*4..+3 (>=30 dead), Whh0 resident
// f16 B-frags (64 reg), src = EW gather prefetched 1 step (rows 0..7 only).
// MFMA rows 8..15: A rows read zeroed LDS rows -> outputs discarded (never
// stored). Phase B: wave owns row `wave`, lane l<60 owns dims {2l,2l+1}.
__global__ __launch_bounds__(512, 4) void k_rec0(const float* __restrict__ Whh,
                                                 const float* __restrict__ EW,
                                                 const int* __restrict__ x,
                                                 _Float16* __restrict__ hb0)
{
  __shared__ float gLs[TB0][GP];                   // 15488 B
  __shared__ __align__(16) _Float16 hLh[16][HP];   //  4352 B (rows 8..15 stay 0)
  __shared__ int xL[TB0*SEQ];                      //   512 B

  const int tid  = threadIdx.x;
  const int wave = tid >> 6, lane = tid & 63;
  const int cl   = lane & 15, quad = lane >> 4;
  const int b0   = blockIdx.x * TB0;

  for (int i = tid; i < TB0*SEQ; i += 512) xL[i] = x[b0*SEQ + i];
  for (int i = tid; i < 16*HP; i += 512) (&hLh[0][0])[i] = (_Float16)0.f;
  __syncthreads();

  v8h Bf[4][4];
  #pragma unroll
  for (int i = 0; i < 4; ++i) {
    const int nt = wave*4 + i;
    const bool vld = (nt < 30);
    const int n = vld ? nt*16 + cl : 0;
    #pragma unroll
    for (int kt = 0; kt < 4; ++kt) {
      const int k0 = kt*32 + quad*8;
      v8h f = {0,0,0,0,0,0,0,0};
      if (vld && k0 < DIM) {
        float4 q0 = *(const float4*)(Whh + n*DIM + k0);
        float4 q1 = *(const float4*)(Whh + n*DIM + k0 + 4);
        f[0]=(_Float16)q0.x; f[1]=(_Float16)q0.y; f[2]=(_Float16)q0.z; f[3]=(_Float16)q0.w;
        f[4]=(_Float16)q1.x; f[5]=(_Float16)q1.y; f[6]=(_Float16)q1.z; f[7]=(_Float16)q1.w;
      }
      Bf[i][kt] = f;
    }
  }

  float srcv[4][4] = {};
  auto load_src = [&](int t) {
    if (quad < 2) {      // output rows quad*4+r in 0..7 only
      #pragma unroll
      for (int i = 0; i < 4; ++i) {
        const int nt = wave*4 + i;
        if (nt < 30) {
          const int n = nt*16 + cl;
          #pragma unroll
          for (int r = 0; r < 4; ++r)
            srcv[i][r] = EW[(size_t)xL[(quad*4 + r)*SEQ + t]*H4 + n];
        }
      }
    }
  };
  load_src(0);

  // phase-B mapping: wave owns row `wave`; lane l<60 owns dims {2l,2l+1}
  const int row = wave;
  const bool act = lane < 60;
  const int d0   = lane*2;
  float C[2] = {0.f, 0.f};

  for (int t = 0; t < SEQ; ++t) {
    __syncthreads();   // hLh (prev phase B / init) visible
    v4f acc[4];
    #pragma unroll
    for (int i = 0; i < 4; ++i) {
      acc[i][0]=srcv[i][0]; acc[i][1]=srcv[i][1];
      acc[i][2]=srcv[i][2]; acc[i][3]=srcv[i][3];
    }
    #pragma unroll
    for (int kt = 0; kt < 4; ++kt) {
      v8h Af = *(const v8h*)&hLh[cl][kt*32 + quad*8];
      #pragma unroll
      for (int i = 0; i < 4; ++i)
        if (wave*4 + i < 30)
          acc[i] = __builtin_amdgcn_mfma_f32_16x16x32_f16(Af, Bf[i][kt], acc[i], 0, 0, 0);
    }
    if (t + 1 < SEQ) load_src(t + 1);
    if (quad < 2) {
      #pragma unroll
      for (int i = 0; i < 4; ++i) {
        const int nt = wave*4 + i;
        if (nt < 30) {
          #pragma unroll
          for (int r = 0; r < 4; ++r)
            gLs[quad*4 + r][nt*16 + cl] = acc[i][r];
        }
      }
    }
    __syncthreads();   // gates visible
    if (act) {
      const float2 gi = *(const float2*)&gLs[row][d0      ];
      const float2 gf = *(const float2*)&gLs[row][d0 + 120];
      const float2 gg = *(const float2*)&gLs[row][d0 + 240];
      const float2 go = *(const float2*)&gLs[row][d0 + 360];
      float h2[2];
      #pragma unroll
      for (int k = 0; k < 2; ++k) {
        const float vi = k ? gi.y : gi.x, vf = k ? gf.y : gf.x;
        const float vg = k ? gg.y : gg.x, vo = k ? go.y : go.x;
        const float si = 1.f / (1.f + __expf(-vi));
        const float sf = 1.f / (1.f + __expf(-vf));
        const float tg = 1.f - 2.f / (__expf(2.f*vg) + 1.f);
        const float so = 1.f / (1.f + __expf(-vo));
        const float c  = sf * C[k] + si * tg;
        C[k] = c;
        const float tc = 1.f - 2.f / (__expf(2.f*c) + 1.f);
        h2[k] = so * tc;
      }
      *(u32*)&hLh[row][d0] = packh2(h2[0], h2[1]);
      *(u32*)&hb0[((size_t)t*BSZ + b0 + row)*KP + d0] = packh2(h2[0], h2[1]);
    } else {
      // lanes 60..63: zero hb0 pad cols 120..127 (2 per lane)
      *(u32*)&hb0[((size_t)t*BSZ + b0 + row)*KP + 120 + 2*(lane - 60)] = 0u;
    }
  }
}

// ---------------- k_rec1: LSTM layer 1 + shuffle-LN + fused head (EXACT R6) ----------------
__global__ __launch_bounds__(512) void k_rec1(const float* __restrict__ Wih1,
                                              const float* __restrict__ Whh1,
                                              const float* __restrict__ b1s,
                                              const _Float16* __restrict__ hb0,
                                              const float* __restrict__ gamma,
                                              const float* __restrict__ beta,
                                              const u16* __restrict__ embP,
                                              float* __restrict__ out)
{
  __shared__ float gLs[TB][GP];                    //  30976 B
  __shared__ __align__(16) _Float16 hLh[TB][HP];   //   4352 B
  __shared__ __align__(16) u16 hnL[TB][HP];        //   4352 B (LN'd h, bf16)
  __shared__ __align__(16) u16 embL[NPAD][HP];     // 121856 B (tied embedding, bf16)

  const int tid  = threadIdx.x;
  const int wave = tid >> 6, lane = tid & 63;
  const int cl   = lane & 15, quad = lane >> 4;
  const int b0   = blockIdx.x * TB;

  for (int i = tid; i < TB*HP; i += 512) (&hLh[0][0])[i] = (_Float16)0.f;
  // stage embP [448][128] -> embL [448][HP] (16 B chunks; 14 iters/thread)
  for (int c = tid; c < NPAD*16; c += 512) {
    const int rw = c >> 4, c16 = c & 15;
    *(v8bf*)&embL[rw][c16*8] = *(const v8bf*)&embP[(size_t)rw*KP + c16*8];
  }

  v8h Bi[4][4], Bh[4][4];
  float bias[4];
  #pragma unroll
  for (int i = 0; i < 4; ++i) {
    const int nt = wave*4 + i;
    const bool vld = (nt < 30);
    const int n = vld ? nt*16 + cl : 0;
    bias[i] = vld ? b1s[n] : 0.f;
    #pragma unroll
    for (int kt = 0; kt < 4; ++kt) {
      const int k0 = kt*32 + quad*8;
      v8h fi = {0,0,0,0,0,0,0,0}, fh = {0,0,0,0,0,0,0,0};
      if (vld && k0 < DIM) {
        float4 q0 = *(const float4*)(Wih1 + n*DIM + k0);
        float4 q1 = *(const float4*)(Wih1 + n*DIM + k0 + 4);
        fi[0]=(_Float16)q0.x; fi[1]=(_Float16)q0.y; fi[2]=(_Float16)q0.z; fi[3]=(_Float16)q0.w;
        fi[4]=(_Float16)q1.x; fi[5]=(_Float16)q1.y; fi[6]=(_Float16)q1.z; fi[7]=(_Float16)q1.w;
        float4 p0 = *(const float4*)(Whh1 + n*DIM + k0);
        float4 p1 = *(const float4*)(Whh1 + n*DIM + k0 + 4);
        fh[0]=(_Float16)p0.x; fh[1]=(_Float16)p0.y; fh[2]=(_Float16)p0.z; fh[3]=(_Float16)p0.w;
        fh[4]=(_Float16)p1.x; fh[5]=(_Float16)p1.y; fh[6]=(_Float16)p1.z; fh[7]=(_Float16)p1.w;
      }
      Bi[i][kt] = fi;
      Bh[i][kt] = fh;
    }
  }

  // phase-B mapping
  const int prow = wave*2;
  const bool act = lane < 60;
  const int d0   = lane*2;
  float gmm[2] = {0.f, 0.f}, bta[2] = {0.f, 0.f};
  if (act) {
    gmm[0] = gamma[d0]; gmm[1] = gamma[d0+1];
    bta[0] = beta[d0];  bta[1] = beta[d0+1];
  }
  float C[2][2] = {{0.f,0.f},{0.f,0.f}};

  // A0 prefetch (t=0)
  v8h A0n[4];
  #pragma unroll
  for (int kt = 0; kt < 4; ++kt)
    A0n[kt] = *(const v8h*)&hb0[((size_t)0*BSZ + b0 + cl)*KP + kt*32 + quad*8];
  __syncthreads();

  for (int t = 0; t < SEQ; ++t) {
    v8h A0c[4], A1[4];
    #pragma unroll
    for (int kt = 0; kt < 4; ++kt) A0c[kt] = A0n[kt];
    #pragma unroll
    for (int kt = 0; kt < 4; ++kt)
      A1[kt] = *(const v8h*)&hLh[cl][kt*32 + quad*8];
    if (t + 1 < SEQ) {
      #pragma unroll
      for (int kt = 0; kt < 4; ++kt)
        A0n[kt] = *(const v8h*)&hb0[((size_t)(t+1)*BSZ + b0 + cl)*KP + kt*32 + quad*8];
    }
    v4f acc[4];
    #pragma unroll
    for (int i = 0; i < 4; ++i)
      acc[i] = (v4f){bias[i], bias[i], bias[i], bias[i]};
    #pragma unroll
    for (int i = 0; i < 4; ++i)
      if (wave*4 + i < 30) {
        #pragma unroll
        for (int kt = 0; kt < 4; ++kt) {
          acc[i] = __builtin_amdgcn_mfma_f32_16x16x32_f16(A0c[kt], Bi[i][kt], acc[i], 0, 0, 0);
          acc[i] = __builtin_amdgcn_mfma_f32_16x16x32_f16(A1[kt],  Bh[i][kt], acc[i], 0, 0, 0);
        }
      }
    #pragma unroll
    for (int i = 0; i < 4; ++i) {
      const int nt = wave*4 + i;
      if (nt < 30) {
        #pragma unroll
        for (int r = 0; r < 4; ++r)
          gLs[quad*4 + r][nt*16 + cl] = acc[i][r];
      }
    }
    __syncthreads();   // sync1: gates visible
    float h2[2][2] = {{0.f,0.f},{0.f,0.f}};
    float s1[2] = {0.f, 0.f}, s2[2] = {0.f, 0.f};
    #pragma unroll
    for (int rr = 0; rr < 2; ++rr) {
      const int row = prow + rr;
      if (act) {
        const float2 gi = *(const float2*)&gLs[row][d0      ];
        const float2 gf = *(const float2*)&gLs[row][d0 + 120];
        const float2 gg = *(const float2*)&gLs[row][d0 + 240];
        const float2 go = *(const float2*)&gLs[row][d0 + 360];
        #pragma unroll
        for (int k = 0; k < 2; ++k) {
          const float vi = k ? gi.y : gi.x, vf = k ? gf.y : gf.x;
          const float vg = k ? gg.y : gg.x, vo = k ? go.y : go.x;
          const float si = 1.f / (1.f + __expf(-vi));
          const float sf = 1.f / (1.f + __expf(-vf));
          const float tg = 1.f - 2.f / (__expf(2.f*vg) + 1.f);
          const float so = 1.f / (1.f + __expf(-vo));
          const float c  = sf * C[rr][k] + si * tg;
          C[rr][k] = c;
          const float tc = 1.f - 2.f / (__expf(2.f*c) + 1.f);
          const float h  = so * tc;
          h2[rr][k] = h;
          s1[rr] += h;
          s2[rr] = fmaf(h, h, s2[rr]);
        }
        *(u32*)&hLh[row][d0] = packh2(h2[rr][0], h2[rr][1]);
      }
    }
    // LN reduction across the wave (all 64 lanes participate; idle lanes add 0)
    #pragma unroll
    for (int m = 32; m >= 1; m >>= 1) {
      s1[0] += __shfl_xor(s1[0], m);
      s2[0] += __shfl_xor(s2[0], m);
      s1[1] += __shfl_xor(s1[1], m);
      s2[1] += __shfl_xor(s2[1], m);
    }
    #pragma unroll
    for (int rr = 0; rr < 2; ++rr) {
      const int row = prow + rr;
      const float mu = s1[rr] * (1.f/DIM);
      const float var = s2[rr] * (1.f/DIM) - mu*mu;
      const float rs = rsqrtf(var + 1e-5f);
      if (act) {
        const float v0 = fmaf((h2[rr][0] - mu)*rs, gmm[0], bta[0]);
        const float v1 = fmaf((h2[rr][1] - mu)*rs, gmm[1], bta[1]);
        *(u32*)&hnL[row][d0] = (u32)f2bf(v0) | ((u32)f2bf(v1) << 16);
      } else {
        *(u32*)&hnL[row][120 + 2*(lane - 60)] = 0u;   // zero pad cols
      }
    }
    __syncthreads();   // sync2: hLh + hnL stable

    // ---- fused tied-embedding head for step t (from LDS, stores fire&forget)
    {
      v8bf a[4];
      #pragma unroll
      for (int kt = 0; kt < 4; ++kt)
        a[kt] = *(const v8bf*)&hnL[cl][kt*32 + quad*8];
      #pragma unroll
      for (int j = 0; j < 4; ++j) {
        const int nt = wave + 8*j;            // waves 0-3: 4 tiles, 4-7: 3 tiles
        if (nt < NT_HEAD) {
          const int n = nt*16 + cl;
          v8bf bfr[4];
          #pragma unroll
          for (int kt = 0; kt < 4; ++kt)
            bfr[kt] = *(const v8bf*)&embL[n][kt*32 + quad*8];
          v4f hacc = {0.f, 0.f, 0.f, 0.f};
          #pragma unroll
          for (int kt = 0; kt < 4; ++kt)
            hacc = __builtin_amdgcn_mfma_f32_16x16x32_bf16(a[kt], bfr[kt], hacc, 0, 0, 0);
          if (n < VSZ) {
            #pragma unroll
            for (int r = 0; r < 4; ++r)
              out[((size_t)(b0 + quad*4 + r)*SEQ + t)*VSZ + n] = hacc[r];
          }
        }
      }
    }
  }
}

// ---------------- launch ----------------
extern "C" void kernel_launch(void* const* d_in, const int* in_sizes, int n_in,
                              void* d_out, int out_size, void* d_ws, size_t ws_size,
                              hipStream_t stream)
{
  (void)in_sizes; (void)n_in; (void)out_size; (void)ws_size;
  const int*   x     = (const int*)d_in[0];
  const float* embed = (const float*)d_in[1];
  const float* Wih0  = (const float*)d_in[2];
  const float* Whh0  = (const float*)d_in[3];
  const float* bih0  = (const float*)d_in[4];
  const float* bhh0  = (const float*)d_in[5];
  const float* Wih1  = (const float*)d_in[6];
  const float* Whh1  = (const float*)d_in[7];
  const float* bih1  = (const float*)d_in[8];
  const float* bhh1  = (const float*)d_in[9];
  const float* gamma = (const float*)d_in[10];
  const float* beta  = (const float*)d_in[11];

  char* ws = (char*)d_ws;
  float*     EW   = (float*)(ws + EW_OFF);
  float*     b1s  = (float*)(ws + B1S_OFF);
  u16*       embP = (u16*)(ws + EMBP_OFF);
  _Float16*  hb0  = (_Float16*)(ws + HB0_OFF);

  k_ew   <<<VSZ, 512, 0, stream>>>(embed, Wih0, bih0, bhh0, EW);
  k_prep2<<<226, 256, 0, stream>>>(embed, bih1, bhh1, embP, b1s);
  k_rec0 <<<BSZ/TB0, 512, 0, stream>>>(Whh0, EW, x, hb0);
  k_rec1 <<<BSZ/TB, 512, 0, stream>>>(Wih1, Whh1, b1s, hb0, gamma, beta, embP, (float*)d_out);
}

// Round 7
// 310.500 us; speedup vs baseline: 1.7651x; 1.2967x over previous
//
#include <hip/hip_runtime.h>

// LSTMNextToken: embed-gather -> 2x LSTM -> LayerNorm -> tied-embedding head.
// I/O dtypes: float tensors are float32; x is int32. Internals f16/bf16 MFMA.
//
// R12 pipeline (= R11 with k_rec0 launch_bounds fixed to (512,2)):
//  k_ew    : EW[v][g] = embed[v]@Wih0^T + bih0 + bhh0       (433x480 f32, L2-resident)
//  k_prep2 : embP bf16 [448][128] zero-padded; b1s = bih1+bhh1 (f32)
//  k_rec0  : TB0=8, grid 512, launch_bounds(512,2) -> 128-reg cap, ~115 used,
//            2 blocks/CU. Wave owns 4 n-tiles (Whh0 resident 64 reg) + 1
//            phase-B row. MFMA rows 8..15 are zero garbage (never stored).
//  k_rec1  : EXACT R6: TB=16, grid 256, MFMA LSTM layer 1 + shuffle-LN +
//            fused tied-embedding head (embL staged in LDS).
// LAUNCH_BOUNDS SEMANTICS (measured R9/R11): 2nd arg = min BLOCKS per CU
// (CUDA semantics). (512,4) -> 64-reg cap (R11: spill, 520MB FETCH, 200us).
// (512,2) -> 128-reg cap = same as plain (512), but guarantees 2-block
// occupancy target. R11 also verified TB0=8 correctness (absmax 3.9e-3),
// localizing R10's failure to the rec1/w1F/head side.

#define VSZ 433
#define DIM 120
#define BSZ 4096
#define SEQ 16
#define H4  480
#define MTOT (BSZ*SEQ)   // 65536
#define KP  128          // padded K for MFMA
#define NPAD 448         // padded vocab for head
#define NT_HEAD (NPAD/16) // 28 head n-tiles
#define TB  16           // batch rows per rec1 block
#define TB0 8            // batch rows per rec0 block (2 blocks/CU)
#define GP  484          // gates LDS row pad (484%32=4 -> 2-way banks = free)
#define HP  136          // h-state LDS row pad in f16/bf16

typedef unsigned int   u32;
typedef unsigned short u16;
typedef __attribute__((ext_vector_type(8))) short    v8bf; // 8 x bf16
typedef __attribute__((ext_vector_type(8))) _Float16 v8h;  // 8 x f16
typedef __attribute__((ext_vector_type(4))) float    v4f;  // MFMA acc

__device__ __forceinline__ u16 f2bf(float f){ // RNE
  union{float f;u32 u;}z; z.f=f;
  u32 u = z.u + 0x7fffu + ((z.u>>16)&1u);
  return (u16)(u>>16);
}
__device__ __forceinline__ u32 packh2(float a, float b){
  union{_Float16 h[2]; u32 u;} z;
  z.h[0] = (_Float16)a; z.h[1] = (_Float16)b;
  return z.u;
}

// ---------------- workspace layout (bytes, 256-aligned) ----------------
#define EW_OFF   0u          // 433*480*4   = 831360
#define B1S_OFF  831488u     // 480*4       = 1920
#define EMBP_OFF 833408u     // 448*128*2   = 114688
#define HB0_OFF  948096u     // 65536*128*2 = 16777216  (f16, t-major)

// ---------------- k_ew ----------------
__global__ __launch_bounds__(512) void k_ew(const float* __restrict__ embed,
                                            const float* __restrict__ Wih0,
                                            const float* __restrict__ bih0,
                                            const float* __restrict__ bhh0,
                                            float* __restrict__ EW)
{
  __shared__ float e[DIM];
  const int v = blockIdx.x, tid = threadIdx.x;
  if (tid < DIM) e[tid] = embed[v*DIM + tid];
  __syncthreads();
  if (tid < H4) {
    float acc = bih0[tid] + bhh0[tid];
    #pragma unroll
    for (int k0 = 0; k0 < DIM; k0 += 4) {
      float4 w = *(const float4*)(Wih0 + tid*DIM + k0);
      acc = fmaf(e[k0+0], w.x, acc);
      acc = fmaf(e[k0+1], w.y, acc);
      acc = fmaf(e[k0+2], w.z, acc);
      acc = fmaf(e[k0+3], w.w, acc);
    }
    EW[v*H4 + tid] = acc;
  }
}

// ---------------- k_prep2: embP bf16 padded + b1s ----------------
__global__ __launch_bounds__(256) void k_prep2(const float* __restrict__ embed,
                                               const float* __restrict__ bih1,
                                               const float* __restrict__ bhh1,
                                               u16* __restrict__ embP,
                                               float* __restrict__ b1s)
{
  const int idx = blockIdx.x*256 + threadIdx.x;
  if (idx < NPAD*KP) {
    int n = idx >> 7, k = idx & 127;
    embP[idx] = (n < VSZ && k < DIM) ? f2bf(embed[n*DIM + k]) : (u16)0;
  } else if (idx < NPAD*KP + H4) {
    int g = idx - NPAD*KP;
    b1s[g] = bih1[g] + bhh1[g];
  }
}

// ---------------- k_rec0: MFMA LSTM layer 0, TB0=8, 2 blocks/CU ----------------
// 512 thr = 8 waves. Wave owns n-tiles wave*4..+3 (>=30 dead), Whh0 resident
// f16 B-frags (64 reg), src = EW gather prefetched 1 step (rows 0..7 only).
// MFMA rows 8..15: A rows read zeroed LDS rows -> outputs discarded (never
// stored). Phase B: wave owns row `wave`, lane l<60 owns dims {2l,2l+1}.
__global__ __launch_bounds__(512, 2) void k_rec0(const float* __restrict__ Whh,
                                                 const float* __restrict__ EW,
                                                 const int* __restrict__ x,
                                                 _Float16* __restrict__ hb0)
{
  __shared__ float gLs[TB0][GP];                   // 15488 B
  __shared__ __align__(16) _Float16 hLh[16][HP];   //  4352 B (rows 8..15 stay 0)
  __shared__ int xL[TB0*SEQ];                      //   512 B

  const int tid  = threadIdx.x;
  const int wave = tid >> 6, lane = tid & 63;
  const int cl   = lane & 15, quad = lane >> 4;
  const int b0   = blockIdx.x * TB0;

  for (int i = tid; i < TB0*SEQ; i += 512) xL[i] = x[b0*SEQ + i];
  for (int i = tid; i < 16*HP; i += 512) (&hLh[0][0])[i] = (_Float16)0.f;
  __syncthreads();

  v8h Bf[4][4];
  #pragma unroll
  for (int i = 0; i < 4; ++i) {
    const int nt = wave*4 + i;
    const bool vld = (nt < 30);
    const int n = vld ? nt*16 + cl : 0;
    #pragma unroll
    for (int kt = 0; kt < 4; ++kt) {
      const int k0 = kt*32 + quad*8;
      v8h f = {0,0,0,0,0,0,0,0};
      if (vld && k0 < DIM) {
        float4 q0 = *(const float4*)(Whh + n*DIM + k0);
        float4 q1 = *(const float4*)(Whh + n*DIM + k0 + 4);
        f[0]=(_Float16)q0.x; f[1]=(_Float16)q0.y; f[2]=(_Float16)q0.z; f[3]=(_Float16)q0.w;
        f[4]=(_Float16)q1.x; f[5]=(_Float16)q1.y; f[6]=(_Float16)q1.z; f[7]=(_Float16)q1.w;
      }
      Bf[i][kt] = f;
    }
  }

  float srcv[4][4] = {};
  auto load_src = [&](int t) {
    if (quad < 2) {      // output rows quad*4+r in 0..7 only
      #pragma unroll
      for (int i = 0; i < 4; ++i) {
        const int nt = wave*4 + i;
        if (nt < 30) {
          const int n = nt*16 + cl;
          #pragma unroll
          for (int r = 0; r < 4; ++r)
            srcv[i][r] = EW[(size_t)xL[(quad*4 + r)*SEQ + t]*H4 + n];
        }
      }
    }
  };
  load_src(0);

  // phase-B mapping: wave owns row `wave`; lane l<60 owns dims {2l,2l+1}
  const int row = wave;
  const bool act = lane < 60;
  const int d0   = lane*2;
  float C[2] = {0.f, 0.f};

  for (int t = 0; t < SEQ; ++t) {
    __syncthreads();   // hLh (prev phase B / init) visible
    v4f acc[4];
    #pragma unroll
    for (int i = 0; i < 4; ++i) {
      acc[i][0]=srcv[i][0]; acc[i][1]=srcv[i][1];
      acc[i][2]=srcv[i][2]; acc[i][3]=srcv[i][3];
    }
    #pragma unroll
    for (int kt = 0; kt < 4; ++kt) {
      v8h Af = *(const v8h*)&hLh[cl][kt*32 + quad*8];
      #pragma unroll
      for (int i = 0; i < 4; ++i)
        if (wave*4 + i < 30)
          acc[i] = __builtin_amdgcn_mfma_f32_16x16x32_f16(Af, Bf[i][kt], acc[i], 0, 0, 0);
    }
    if (t + 1 < SEQ) load_src(t + 1);
    if (quad < 2) {
      #pragma unroll
      for (int i = 0; i < 4; ++i) {
        const int nt = wave*4 + i;
        if (nt < 30) {
          #pragma unroll
          for (int r = 0; r < 4; ++r)
            gLs[quad*4 + r][nt*16 + cl] = acc[i][r];
        }
      }
    }
    __syncthreads();   // gates visible
    if (act) {
      const float2 gi = *(const float2*)&gLs[row][d0      ];
      const float2 gf = *(const float2*)&gLs[row][d0 + 120];
      const float2 gg = *(const float2*)&gLs[row][d0 + 240];
      const float2 go = *(const float2*)&gLs[row][d0 + 360];
      float h2[2];
      #pragma unroll
      for (int k = 0; k < 2; ++k) {
        const float vi = k ? gi.y : gi.x, vf = k ? gf.y : gf.x;
        const float vg = k ? gg.y : gg.x, vo = k ? go.y : go.x;
        const float si = 1.f / (1.f + __expf(-vi));
        const float sf = 1.f / (1.f + __expf(-vf));
        const float tg = 1.f - 2.f / (__expf(2.f*vg) + 1.f);
        const float so = 1.f / (1.f + __expf(-vo));
        const float c  = sf * C[k] + si * tg;
        C[k] = c;
        const float tc = 1.f - 2.f / (__expf(2.f*c) + 1.f);
        h2[k] = so * tc;
      }
      *(u32*)&hLh[row][d0] = packh2(h2[0], h2[1]);
      *(u32*)&hb0[((size_t)t*BSZ + b0 + row)*KP + d0] = packh2(h2[0], h2[1]);
    } else {
      // lanes 60..63: zero hb0 pad cols 120..127 (2 per lane)
      *(u32*)&hb0[((size_t)t*BSZ + b0 + row)*KP + 120 + 2*(lane - 60)] = 0u;
    }
  }
}

// ---------------- k_rec1: LSTM layer 1 + shuffle-LN + fused head (EXACT R6) ----------------
__global__ __launch_bounds__(512) void k_rec1(const float* __restrict__ Wih1,
                                              const float* __restrict__ Whh1,
                                              const float* __restrict__ b1s,
                                              const _Float16* __restrict__ hb0,
                                              const float* __restrict__ gamma,
                                              const float* __restrict__ beta,
                                              const u16* __restrict__ embP,
                                              float* __restrict__ out)
{
  __shared__ float gLs[TB][GP];                    //  30976 B
  __shared__ __align__(16) _Float16 hLh[TB][HP];   //   4352 B
  __shared__ __align__(16) u16 hnL[TB][HP];        //   4352 B (LN'd h, bf16)
  __shared__ __align__(16) u16 embL[NPAD][HP];     // 121856 B (tied embedding, bf16)

  const int tid  = threadIdx.x;
  const int wave = tid >> 6, lane = tid & 63;
  const int cl   = lane & 15, quad = lane >> 4;
  const int b0   = blockIdx.x * TB;

  for (int i = tid; i < TB*HP; i += 512) (&hLh[0][0])[i] = (_Float16)0.f;
  // stage embP [448][128] -> embL [448][HP] (16 B chunks; 14 iters/thread)
  for (int c = tid; c < NPAD*16; c += 512) {
    const int rw = c >> 4, c16 = c & 15;
    *(v8bf*)&embL[rw][c16*8] = *(const v8bf*)&embP[(size_t)rw*KP + c16*8];
  }

  v8h Bi[4][4], Bh[4][4];
  float bias[4];
  #pragma unroll
  for (int i = 0; i < 4; ++i) {
    const int nt = wave*4 + i;
    const bool vld = (nt < 30);
    const int n = vld ? nt*16 + cl : 0;
    bias[i] = vld ? b1s[n] : 0.f;
    #pragma unroll
    for (int kt = 0; kt < 4; ++kt) {
      const int k0 = kt*32 + quad*8;
      v8h fi = {0,0,0,0,0,0,0,0}, fh = {0,0,0,0,0,0,0,0};
      if (vld && k0 < DIM) {
        float4 q0 = *(const float4*)(Wih1 + n*DIM + k0);
        float4 q1 = *(const float4*)(Wih1 + n*DIM + k0 + 4);
        fi[0]=(_Float16)q0.x; fi[1]=(_Float16)q0.y; fi[2]=(_Float16)q0.z; fi[3]=(_Float16)q0.w;
        fi[4]=(_Float16)q1.x; fi[5]=(_Float16)q1.y; fi[6]=(_Float16)q1.z; fi[7]=(_Float16)q1.w;
        float4 p0 = *(const float4*)(Whh1 + n*DIM + k0);
        float4 p1 = *(const float4*)(Whh1 + n*DIM + k0 + 4);
        fh[0]=(_Float16)p0.x; fh[1]=(_Float16)p0.y; fh[2]=(_Float16)p0.z; fh[3]=(_Float16)p0.w;
        fh[4]=(_Float16)p1.x; fh[5]=(_Float16)p1.y; fh[6]=(_Float16)p1.z; fh[7]=(_Float16)p1.w;
      }
      Bi[i][kt] = fi;
      Bh[i][kt] = fh;
    }
  }

  // phase-B mapping
  const int prow = wave*2;
  const bool act = lane < 60;
  const int d0   = lane*2;
  float gmm[2] = {0.f, 0.f}, bta[2] = {0.f, 0.f};
  if (act) {
    gmm[0] = gamma[d0]; gmm[1] = gamma[d0+1];
    bta[0] = beta[d0];  bta[1] = beta[d0+1];
  }
  float C[2][2] = {{0.f,0.f},{0.f,0.f}};

  // A0 prefetch (t=0)
  v8h A0n[4];
  #pragma unroll
  for (int kt = 0; kt < 4; ++kt)
    A0n[kt] = *(const v8h*)&hb0[((size_t)0*BSZ + b0 + cl)*KP + kt*32 + quad*8];
  __syncthreads();

  for (int t = 0; t < SEQ; ++t) {
    v8h A0c[4], A1[4];
    #pragma unroll
    for (int kt = 0; kt < 4; ++kt) A0c[kt] = A0n[kt];
    #pragma unroll
    for (int kt = 0; kt < 4; ++kt)
      A1[kt] = *(const v8h*)&hLh[cl][kt*32 + quad*8];
    if (t + 1 < SEQ) {
      #pragma unroll
      for (int kt = 0; kt < 4; ++kt)
        A0n[kt] = *(const v8h*)&hb0[((size_t)(t+1)*BSZ + b0 + cl)*KP + kt*32 + quad*8];
    }
    v4f acc[4];
    #pragma unroll
    for (int i = 0; i < 4; ++i)
      acc[i] = (v4f){bias[i], bias[i], bias[i], bias[i]};
    #pragma unroll
    for (int i = 0; i < 4; ++i)
      if (wave*4 + i < 30) {
        #pragma unroll
        for (int kt = 0; kt < 4; ++kt) {
          acc[i] = __builtin_amdgcn_mfma_f32_16x16x32_f16(A0c[kt], Bi[i][kt], acc[i], 0, 0, 0);
          acc[i] = __builtin_amdgcn_mfma_f32_16x16x32_f16(A1[kt],  Bh[i][kt], acc[i], 0, 0, 0);
        }
      }
    #pragma unroll
    for (int i = 0; i < 4; ++i) {
      const int nt = wave*4 + i;
      if (nt < 30) {
        #pragma unroll
        for (int r = 0; r < 4; ++r)
          gLs[quad*4 + r][nt*16 + cl] = acc[i][r];
      }
    }
    __syncthreads();   // sync1: gates visible
    float h2[2][2] = {{0.f,0.f},{0.f,0.f}};
    float s1[2] = {0.f, 0.f}, s2[2] = {0.f, 0.f};
    #pragma unroll
    for (int rr = 0; rr < 2; ++rr) {
      const int row = prow + rr;
      if (act) {
        const float2 gi = *(const float2*)&gLs[row][d0      ];
        const float2 gf = *(const float2*)&gLs[row][d0 + 120];
        const float2 gg = *(const float2*)&gLs[row][d0 + 240];
        const float2 go = *(const float2*)&gLs[row][d0 + 360];
        #pragma unroll
        for (int k = 0; k < 2; ++k) {
          const float vi = k ? gi.y : gi.x, vf = k ? gf.y : gf.x;
          const float vg = k ? gg.y : gg.x, vo = k ? go.y : go.x;
          const float si = 1.f / (1.f + __expf(-vi));
          const float sf = 1.f / (1.f + __expf(-vf));
          const float tg = 1.f - 2.f / (__expf(2.f*vg) + 1.f);
          const float so = 1.f / (1.f + __expf(-vo));
          const float c  = sf * C[rr][k] + si * tg;
          C[rr][k] = c;
          const float tc = 1.f - 2.f / (__expf(2.f*c) + 1.f);
          const float h  = so * tc;
          h2[rr][k] = h;
          s1[rr] += h;
          s2[rr] = fmaf(h, h, s2[rr]);
        }
        *(u32*)&hLh[row][d0] = packh2(h2[rr][0], h2[rr][1]);
      }
    }
    // LN reduction across the wave (all 64 lanes participate; idle lanes add 0)
    #pragma unroll
    for (int m = 32; m >= 1; m >>= 1) {
      s1[0] += __shfl_xor(s1[0], m);
      s2[0] += __shfl_xor(s2[0], m);
      s1[1] += __shfl_xor(s1[1], m);
      s2[1] += __shfl_xor(s2[1], m);
    }
    #pragma unroll
    for (int rr = 0; rr < 2; ++rr) {
      const int row = prow + rr;
      const float mu = s1[rr] * (1.f/DIM);
      const float var = s2[rr] * (1.f/DIM) - mu*mu;
      const float rs = rsqrtf(var + 1e-5f);
      if (act) {
        const float v0 = fmaf((h2[rr][0] - mu)*rs, gmm[0], bta[0]);
        const float v1 = fmaf((h2[rr][1] - mu)*rs, gmm[1], bta[1]);
        *(u32*)&hnL[row][d0] = (u32)f2bf(v0) | ((u32)f2bf(v1) << 16);
      } else {
        *(u32*)&hnL[row][120 + 2*(lane - 60)] = 0u;   // zero pad cols
      }
    }
    __syncthreads();   // sync2: hLh + hnL stable

    // ---- fused tied-embedding head for step t (from LDS, stores fire&forget)
    {
      v8bf a[4];
      #pragma unroll
      for (int kt = 0; kt < 4; ++kt)
        a[kt] = *(const v8bf*)&hnL[cl][kt*32 + quad*8];
      #pragma unroll
      for (int j = 0; j < 4; ++j) {
        const int nt = wave + 8*j;            // waves 0-3: 4 tiles, 4-7: 3 tiles
        if (nt < NT_HEAD) {
          const int n = nt*16 + cl;
          v8bf bfr[4];
          #pragma unroll
          for (int kt = 0; kt < 4; ++kt)
            bfr[kt] = *(const v8bf*)&embL[n][kt*32 + quad*8];
          v4f hacc = {0.f, 0.f, 0.f, 0.f};
          #pragma unroll
          for (int kt = 0; kt < 4; ++kt)
            hacc = __builtin_amdgcn_mfma_f32_16x16x32_bf16(a[kt], bfr[kt], hacc, 0, 0, 0);
          if (n < VSZ) {
            #pragma unroll
            for (int r = 0; r < 4; ++r)
              out[((size_t)(b0 + quad*4 + r)*SEQ + t)*VSZ + n] = hacc[r];
          }
        }
      }
    }
  }
}

// ---------------- launch ----------------
extern "C" void kernel_launch(void* const* d_in, const int* in_sizes, int n_in,
                              void* d_out, int out_size, void* d_ws, size_t ws_size,
                              hipStream_t stream)
{
  (void)in_sizes; (void)n_in; (void)out_size; (void)ws_size;
  const int*   x     = (const int*)d_in[0];
  const float* embed = (const float*)d_in[1];
  const float* Wih0  = (const float*)d_in[2];
  const float* Whh0  = (const float*)d_in[3];
  const float* bih0  = (const float*)d_in[4];
  const float* bhh0  = (const float*)d_in[5];
  const float* Wih1  = (const float*)d_in[6];
  const float* Whh1  = (const float*)d_in[7];
  const float* bih1  = (const float*)d_in[8];
  const float* bhh1  = (const float*)d_in[9];
  const float* gamma = (const float*)d_in[10];
  const float* beta  = (const float*)d_in[11];

  char* ws = (char*)d_ws;
  float*     EW   = (float*)(ws + EW_OFF);
  float*     b1s  = (float*)(ws + B1S_OFF);
  u16*       embP = (u16*)(ws + EMBP_OFF);
  _Float16*  hb0  = (_Float16*)(ws + HB0_OFF);

  k_ew   <<<VSZ, 512, 0, stream>>>(embed, Wih0, bih0, bhh0, EW);
  k_prep2<<<226, 256, 0, stream>>>(embed, bih1, bhh1, embP, b1s);
  k_rec0 <<<BSZ/TB0, 512, 0, stream>>>(Whh0, EW, x, hb0);
  k_rec1 <<<BSZ/TB, 512, 0, stream>>>(Wih1, Whh1, b1s, hb0, gamma, beta, embP, (float*)d_out);
}

// Round 8
// 257.192 us; speedup vs baseline: 2.1310x; 1.2073x over previous
//
#include <hip/hip_runtime.h>

// LSTMNextToken: embed-gather -> 2x LSTM -> LayerNorm -> tied-embedding head.
// I/O dtypes: float tensors are float32; x is int32. Internals f16/bf16 MFMA.
//
// R13 pipeline:
//  k_init : blocks 0..432 = EW precompute (embed@Wih0^T + biases);
//           blocks 433..545 = embP bf16 pad + b1s. (was k_ew + k_prep2)
//  k_rec  : grid 256, TB=16, 512 thr. PHASE 1 = verified R6 k_rec0 loop
//           (layer 0 -> hb0 global, L2-hot). Inline-asm pointer guard +
//           hLh re-zero + barrier. PHASE 2 = verified R6 k_rec1 loop
//           (layer 1 + shuffle-LN + fused tied-embedding head from embL LDS).
// R12 lesson: 2 blocks/CU is unreachable for these MFMA kernels (VGPR=100
// still 1 block/CU; unified VGPR+AGPR + granularity). So R13 instead removes
// the rec0->rec1 GLOBAL barrier (tail + launch gap): block b starts layer 1
// the moment ITS layer-0 chain is done. embL staged in prologue (hidden
// under phase 1). Anti-hoist guard keeps Bi/Bh loads below phase 1 (R9 trap).
// LDS: 30976(gLs)+4352(hLh)+4352(hnL)+121856(embL)+1024(xL) = 162560 B.

#define VSZ 433
#define DIM 120
#define BSZ 4096
#define SEQ 16
#define H4  480
#define KP  128          // padded K for MFMA
#define NPAD 448         // padded vocab for head
#define NT_HEAD (NPAD/16) // 28 head n-tiles
#define TB  16           // batch rows per rec block
#define GP  484          // gates LDS row pad (484%32=4 -> 2-way banks = free)
#define HP  136          // h-state LDS row pad in f16/bf16

typedef unsigned int   u32;
typedef unsigned short u16;
typedef __attribute__((ext_vector_type(8))) short    v8bf; // 8 x bf16
typedef __attribute__((ext_vector_type(8))) _Float16 v8h;  // 8 x f16
typedef __attribute__((ext_vector_type(4))) float    v4f;  // MFMA acc

__device__ __forceinline__ u16 f2bf(float f){ // RNE
  union{float f;u32 u;}z; z.f=f;
  u32 u = z.u + 0x7fffu + ((z.u>>16)&1u);
  return (u16)(u>>16);
}
__device__ __forceinline__ u32 packh2(float a, float b){
  union{_Float16 h[2]; u32 u;} z;
  z.h[0] = (_Float16)a; z.h[1] = (_Float16)b;
  return z.u;
}

// ---------------- workspace layout (bytes, 256-aligned) ----------------
#define EW_OFF   0u          // 433*480*4   = 831360
#define B1S_OFF  831488u     // 480*4       = 1920
#define EMBP_OFF 833408u     // 448*128*2   = 114688
#define HB0_OFF  948096u     // 65536*128*2 = 16777216  (f16, t-major)

#define PREP_BLKS 113        // ceil((448*128 + 480)/512)

// ---------------- k_init: EW precompute + embP/b1s prep ----------------
__global__ __launch_bounds__(512) void k_init(const float* __restrict__ embed,
                                              const float* __restrict__ Wih0,
                                              const float* __restrict__ bih0,
                                              const float* __restrict__ bhh0,
                                              const float* __restrict__ bih1,
                                              const float* __restrict__ bhh1,
                                              float* __restrict__ EW,
                                              u16* __restrict__ embP,
                                              float* __restrict__ b1s)
{
  __shared__ float e[DIM];
  const int tid = threadIdx.x;
  if (blockIdx.x < VSZ) {
    const int v = blockIdx.x;
    if (tid < DIM) e[tid] = embed[v*DIM + tid];
    __syncthreads();
    if (tid < H4) {
      float acc = bih0[tid] + bhh0[tid];
      #pragma unroll
      for (int k0 = 0; k0 < DIM; k0 += 4) {
        float4 w = *(const float4*)(Wih0 + tid*DIM + k0);
        acc = fmaf(e[k0+0], w.x, acc);
        acc = fmaf(e[k0+1], w.y, acc);
        acc = fmaf(e[k0+2], w.z, acc);
        acc = fmaf(e[k0+3], w.w, acc);
      }
      EW[v*H4 + tid] = acc;
    }
  } else {
    const int idx = (blockIdx.x - VSZ)*512 + tid;
    if (idx < NPAD*KP) {
      int n = idx >> 7, k = idx & 127;
      embP[idx] = (n < VSZ && k < DIM) ? f2bf(embed[n*DIM + k]) : (u16)0;
    } else if (idx < NPAD*KP + H4) {
      int g = idx - NPAD*KP;
      b1s[g] = bih1[g] + bhh1[g];
    }
  }
}

// ---------------- k_rec: fused layer0 chain -> layer1 chain + LN + head ----------------
__global__ __launch_bounds__(512) void k_rec(const float* __restrict__ Whh0,
                                             const float* __restrict__ EW,
                                             const int* __restrict__ x,
                                             const float* __restrict__ Wih1,
                                             const float* __restrict__ Whh1,
                                             const float* __restrict__ b1s,
                                             const float* __restrict__ gamma,
                                             const float* __restrict__ beta,
                                             const u16* __restrict__ embP,
                                             _Float16* __restrict__ hb0,
                                             float* __restrict__ out)
{
  __shared__ float gLs[TB][GP];                    //  30976 B (both phases)
  __shared__ __align__(16) _Float16 hLh[TB][HP];   //   4352 B (h0, then h1)
  __shared__ __align__(16) u16 hnL[TB][HP];        //   4352 B (LN'd h1, bf16)
  __shared__ __align__(16) u16 embL[NPAD][HP];     // 121856 B (tied embedding)
  __shared__ int xL[TB*SEQ];                       //   1024 B
  // total 162560 B

  const int tid  = threadIdx.x;
  const int wave = tid >> 6, lane = tid & 63;
  const int cl   = lane & 15, quad = lane >> 4;
  const int b0   = blockIdx.x * TB;

  // ---- prologue staging: xL, hLh zero, embL (embL hidden under phase 1)
  for (int i = tid; i < TB*SEQ; i += 512) xL[i] = x[b0*SEQ + i];
  for (int i = tid; i < TB*HP; i += 512) (&hLh[0][0])[i] = (_Float16)0.f;
  for (int c = tid; c < NPAD*16; c += 512) {
    const int rw = c >> 4, c16 = c & 15;
    *(v8bf*)&embL[rw][c16*8] = *(const v8bf*)&embP[(size_t)rw*KP + c16*8];
  }
  __syncthreads();

  // phase-B mapping (both phases): wave owns rows {2w,2w+1}; lane l<60 owns {2l,2l+1}
  const int prow = wave*2;
  const bool act = lane < 60;
  const int d0   = lane*2;

  // ================= PHASE 1: layer 0 (verified R6 k_rec0) =================
  {
    v8h Bf[4][4];
    #pragma unroll
    for (int i = 0; i < 4; ++i) {
      const int nt = wave*4 + i;
      const bool vld = (nt < 30);
      const int n = vld ? nt*16 + cl : 0;
      #pragma unroll
      for (int kt = 0; kt < 4; ++kt) {
        const int k0 = kt*32 + quad*8;
        v8h f = {0,0,0,0,0,0,0,0};
        if (vld && k0 < DIM) {
          float4 q0 = *(const float4*)(Whh0 + n*DIM + k0);
          float4 q1 = *(const float4*)(Whh0 + n*DIM + k0 + 4);
          f[0]=(_Float16)q0.x; f[1]=(_Float16)q0.y; f[2]=(_Float16)q0.z; f[3]=(_Float16)q0.w;
          f[4]=(_Float16)q1.x; f[5]=(_Float16)q1.y; f[6]=(_Float16)q1.z; f[7]=(_Float16)q1.w;
        }
        Bf[i][kt] = f;
      }
    }

    float srcv[4][4];
    auto load_src = [&](int t) {
      #pragma unroll
      for (int i = 0; i < 4; ++i) {
        const int nt = wave*4 + i;
        if (nt < 30) {
          const int n = nt*16 + cl;
          #pragma unroll
          for (int r = 0; r < 4; ++r)
            srcv[i][r] = EW[(size_t)xL[(quad*4 + r)*SEQ + t]*H4 + n];
        }
      }
    };
    load_src(0);

    float C0[2][2] = {{0.f,0.f},{0.f,0.f}};

    for (int t = 0; t < SEQ; ++t) {
      __syncthreads();   // hLh (prev phase B / init) visible
      v8h Af[4];
      #pragma unroll
      for (int kt = 0; kt < 4; ++kt)
        Af[kt] = *(const v8h*)&hLh[cl][kt*32 + quad*8];
      v4f acc[4];
      #pragma unroll
      for (int i = 0; i < 4; ++i) {
        acc[i][0]=srcv[i][0]; acc[i][1]=srcv[i][1];
        acc[i][2]=srcv[i][2]; acc[i][3]=srcv[i][3];
      }
      #pragma unroll
      for (int i = 0; i < 4; ++i)
        if (wave*4 + i < 30) {
          #pragma unroll
          for (int kt = 0; kt < 4; ++kt)
            acc[i] = __builtin_amdgcn_mfma_f32_16x16x32_f16(Af[kt], Bf[i][kt], acc[i], 0, 0, 0);
        }
      if (t + 1 < SEQ) load_src(t + 1);
      #pragma unroll
      for (int i = 0; i < 4; ++i) {
        const int nt = wave*4 + i;
        if (nt < 30) {
          #pragma unroll
          for (int r = 0; r < 4; ++r)
            gLs[quad*4 + r][nt*16 + cl] = acc[i][r];
        }
      }
      __syncthreads();   // gates visible
      #pragma unroll
      for (int rr = 0; rr < 2; ++rr) {
        const int row = prow + rr;
        if (act) {
          const float2 gi = *(const float2*)&gLs[row][d0      ];
          const float2 gf = *(const float2*)&gLs[row][d0 + 120];
          const float2 gg = *(const float2*)&gLs[row][d0 + 240];
          const float2 go = *(const float2*)&gLs[row][d0 + 360];
          float h2[2];
          #pragma unroll
          for (int k = 0; k < 2; ++k) {
            const float vi = k ? gi.y : gi.x, vf = k ? gf.y : gf.x;
            const float vg = k ? gg.y : gg.x, vo = k ? go.y : go.x;
            const float si = 1.f / (1.f + __expf(-vi));
            const float sf = 1.f / (1.f + __expf(-vf));
            const float tg = 1.f - 2.f / (__expf(2.f*vg) + 1.f);
            const float so = 1.f / (1.f + __expf(-vo));
            const float c  = sf * C0[rr][k] + si * tg;
            C0[rr][k] = c;
            const float tc = 1.f - 2.f / (__expf(2.f*c) + 1.f);
            h2[k] = so * tc;
          }
          *(u32*)&hLh[row][d0] = packh2(h2[0], h2[1]);
          *(u32*)&hb0[((size_t)t*BSZ + b0 + row)*KP + d0] = packh2(h2[0], h2[1]);
        } else {
          // lanes 60..63: zero hb0 pad cols 120..127 (2 per lane)
          *(u32*)&hb0[((size_t)t*BSZ + b0 + row)*KP + 120 + 2*(lane - 60)] = 0u;
        }
      }
    }
  }

  __syncthreads();   // phase 1 complete: hb0 writes drained + visible block-wide

  // anti-hoist guard: make phase-2 weight pointers opaque so their 128-reg
  // fragment loads cannot be moved above phase 1 (R9 spill trap).
  const float* Wih1p = Wih1;
  const float* Whh1p = Whh1;
  const float* b1sp  = b1s;
  asm volatile("" : "+s"(Wih1p), "+s"(Whh1p), "+s"(b1sp) :: "memory");

  // re-zero hLh for layer-1 state
  for (int i = tid; i < TB*HP; i += 512) (&hLh[0][0])[i] = (_Float16)0.f;

  // ================= PHASE 2: layer 1 + LN + head (verified R6 k_rec1) =================
  v8h Bi[4][4], Bh[4][4];
  float bias[4];
  #pragma unroll
  for (int i = 0; i < 4; ++i) {
    const int nt = wave*4 + i;
    const bool vld = (nt < 30);
    const int n = vld ? nt*16 + cl : 0;
    bias[i] = vld ? b1sp[n] : 0.f;
    #pragma unroll
    for (int kt = 0; kt < 4; ++kt) {
      const int k0 = kt*32 + quad*8;
      v8h fi = {0,0,0,0,0,0,0,0}, fh = {0,0,0,0,0,0,0,0};
      if (vld && k0 < DIM) {
        float4 q0 = *(const float4*)(Wih1p + n*DIM + k0);
        float4 q1 = *(const float4*)(Wih1p + n*DIM + k0 + 4);
        fi[0]=(_Float16)q0.x; fi[1]=(_Float16)q0.y; fi[2]=(_Float16)q0.z; fi[3]=(_Float16)q0.w;
        fi[4]=(_Float16)q1.x; fi[5]=(_Float16)q1.y; fi[6]=(_Float16)q1.z; fi[7]=(_Float16)q1.w;
        float4 p0 = *(const float4*)(Whh1p + n*DIM + k0);
        float4 p1 = *(const float4*)(Whh1p + n*DIM + k0 + 4);
        fh[0]=(_Float16)p0.x; fh[1]=(_Float16)p0.y; fh[2]=(_Float16)p0.z; fh[3]=(_Float16)p0.w;
        fh[4]=(_Float16)p1.x; fh[5]=(_Float16)p1.y; fh[6]=(_Float16)p1.z; fh[7]=(_Float16)p1.w;
      }
      Bi[i][kt] = fi;
      Bh[i][kt] = fh;
    }
  }

  float gmm[2] = {0.f, 0.f}, bta[2] = {0.f, 0.f};
  if (act) {
    gmm[0] = gamma[d0]; gmm[1] = gamma[d0+1];
    bta[0] = beta[d0];  bta[1] = beta[d0+1];
  }
  float C1[2][2] = {{0.f,0.f},{0.f,0.f}};

  // A0 prefetch (t=0) — own block's hb0 rows, L2/L1-hot
  v8h A0n[4];
  #pragma unroll
  for (int kt = 0; kt < 4; ++kt)
    A0n[kt] = *(const v8h*)&hb0[((size_t)0*BSZ + b0 + cl)*KP + kt*32 + quad*8];
  __syncthreads();   // hLh re-zero visible

  for (int t = 0; t < SEQ; ++t) {
    v8h A0c[4], A1[4];
    #pragma unroll
    for (int kt = 0; kt < 4; ++kt) A0c[kt] = A0n[kt];
    #pragma unroll
    for (int kt = 0; kt < 4; ++kt)
      A1[kt] = *(const v8h*)&hLh[cl][kt*32 + quad*8];
    if (t + 1 < SEQ) {
      #pragma unroll
      for (int kt = 0; kt < 4; ++kt)
        A0n[kt] = *(const v8h*)&hb0[((size_t)(t+1)*BSZ + b0 + cl)*KP + kt*32 + quad*8];
    }
    v4f acc[4];
    #pragma unroll
    for (int i = 0; i < 4; ++i)
      acc[i] = (v4f){bias[i], bias[i], bias[i], bias[i]};
    #pragma unroll
    for (int i = 0; i < 4; ++i)
      if (wave*4 + i < 30) {
        #pragma unroll
        for (int kt = 0; kt < 4; ++kt) {
          acc[i] = __builtin_amdgcn_mfma_f32_16x16x32_f16(A0c[kt], Bi[i][kt], acc[i], 0, 0, 0);
          acc[i] = __builtin_amdgcn_mfma_f32_16x16x32_f16(A1[kt],  Bh[i][kt], acc[i], 0, 0, 0);
        }
      }
    #pragma unroll
    for (int i = 0; i < 4; ++i) {
      const int nt = wave*4 + i;
      if (nt < 30) {
        #pragma unroll
        for (int r = 0; r < 4; ++r)
          gLs[quad*4 + r][nt*16 + cl] = acc[i][r];
      }
    }
    __syncthreads();   // sync1: gates visible
    float h2[2][2] = {{0.f,0.f},{0.f,0.f}};
    float s1[2] = {0.f, 0.f}, s2[2] = {0.f, 0.f};
    #pragma unroll
    for (int rr = 0; rr < 2; ++rr) {
      const int row = prow + rr;
      if (act) {
        const float2 gi = *(const float2*)&gLs[row][d0      ];
        const float2 gf = *(const float2*)&gLs[row][d0 + 120];
        const float2 gg = *(const float2*)&gLs[row][d0 + 240];
        const float2 go = *(const float2*)&gLs[row][d0 + 360];
        #pragma unroll
        for (int k = 0; k < 2; ++k) {
          const float vi = k ? gi.y : gi.x, vf = k ? gf.y : gf.x;
          const float vg = k ? gg.y : gg.x, vo = k ? go.y : go.x;
          const float si = 1.f / (1.f + __expf(-vi));
          const float sf = 1.f / (1.f + __expf(-vf));
          const float tg = 1.f - 2.f / (__expf(2.f*vg) + 1.f);
          const float so = 1.f / (1.f + __expf(-vo));
          const float c  = sf * C1[rr][k] + si * tg;
          C1[rr][k] = c;
          const float tc = 1.f - 2.f / (__expf(2.f*c) + 1.f);
          const float h  = so * tc;
          h2[rr][k] = h;
          s1[rr] += h;
          s2[rr] = fmaf(h, h, s2[rr]);
        }
        *(u32*)&hLh[row][d0] = packh2(h2[rr][0], h2[rr][1]);
      }
    }
    // LN reduction across the wave (idle lanes contribute 0)
    #pragma unroll
    for (int m = 32; m >= 1; m >>= 1) {
      s1[0] += __shfl_xor(s1[0], m);
      s2[0] += __shfl_xor(s2[0], m);
      s1[1] += __shfl_xor(s1[1], m);
      s2[1] += __shfl_xor(s2[1], m);
    }
    #pragma unroll
    for (int rr = 0; rr < 2; ++rr) {
      const int row = prow + rr;
      const float mu = s1[rr] * (1.f/DIM);
      const float var = s2[rr] * (1.f/DIM) - mu*mu;
      const float rs = rsqrtf(var + 1e-5f);
      if (act) {
        const float v0 = fmaf((h2[rr][0] - mu)*rs, gmm[0], bta[0]);
        const float v1 = fmaf((h2[rr][1] - mu)*rs, gmm[1], bta[1]);
        *(u32*)&hnL[row][d0] = (u32)f2bf(v0) | ((u32)f2bf(v1) << 16);
      } else {
        *(u32*)&hnL[row][120 + 2*(lane - 60)] = 0u;   // zero pad cols
      }
    }
    __syncthreads();   // sync2: hLh + hnL stable

    // ---- fused tied-embedding head for step t (from LDS, stores fire&forget)
    {
      v8bf a[4];
      #pragma unroll
      for (int kt = 0; kt < 4; ++kt)
        a[kt] = *(const v8bf*)&hnL[cl][kt*32 + quad*8];
      #pragma unroll
      for (int j = 0; j < 4; ++j) {
        const int nt = wave + 8*j;            // waves 0-3: 4 tiles, 4-7: 3 tiles
        if (nt < NT_HEAD) {
          const int n = nt*16 + cl;
          v8bf bfr[4];
          #pragma unroll
          for (int kt = 0; kt < 4; ++kt)
            bfr[kt] = *(const v8bf*)&embL[n][kt*32 + quad*8];
          v4f hacc = {0.f, 0.f, 0.f, 0.f};
          #pragma unroll
          for (int kt = 0; kt < 4; ++kt)
            hacc = __builtin_amdgcn_mfma_f32_16x16x32_bf16(a[kt], bfr[kt], hacc, 0, 0, 0);
          if (n < VSZ) {
            #pragma unroll
            for (int r = 0; r < 4; ++r)
              out[((size_t)(b0 + quad*4 + r)*SEQ + t)*VSZ + n] = hacc[r];
          }
        }
      }
    }
  }
}

// ---------------- launch ----------------
extern "C" void kernel_launch(void* const* d_in, const int* in_sizes, int n_in,
                              void* d_out, int out_size, void* d_ws, size_t ws_size,
                              hipStream_t stream)
{
  (void)in_sizes; (void)n_in; (void)out_size; (void)ws_size;
  const int*   x     = (const int*)d_in[0];
  const float* embed = (const float*)d_in[1];
  const float* Wih0  = (const float*)d_in[2];
  const float* Whh0  = (const float*)d_in[3];
  const float* bih0  = (const float*)d_in[4];
  const float* bhh0  = (const float*)d_in[5];
  const float* Wih1  = (const float*)d_in[6];
  const float* Whh1  = (const float*)d_in[7];
  const float* bih1  = (const float*)d_in[8];
  const float* bhh1  = (const float*)d_in[9];
  const float* gamma = (const float*)d_in[10];
  const float* beta  = (const float*)d_in[11];

  char* ws = (char*)d_ws;
  float*     EW   = (float*)(ws + EW_OFF);
  float*     b1s  = (float*)(ws + B1S_OFF);
  u16*       embP = (u16*)(ws + EMBP_OFF);
  _Float16*  hb0  = (_Float16*)(ws + HB0_OFF);

  k_init<<<VSZ + PREP_BLKS, 512, 0, stream>>>(embed, Wih0, bih0, bhh0, bih1, bhh1,
                                              EW, embP, b1s);
  k_rec <<<BSZ/TB, 512, 0, stream>>>(Whh0, EW, x, Wih1, Whh1, b1s, gamma, beta,
                                     embP, hb0, (float*)d_out);
}